// Round 6
// baseline (655.548 us; speedup 1.0000x reference)
//
#include <hip/hip_runtime.h>
#include <hip/hip_bf16.h>

// GLIFR forward, MI355X.  Pipeline (S kept in bf16, lat accumulates via beta):
//   D0:  mega[ Sff(0), Sff(1) ]                    (320 blocks)
//   rec(0)
//   c=1..9:  mega[ lat(c), out(c-1), Sff(c+1) ]    (360 / 200 blocks)
//            rec(c)
//   D10: mega[ out(9) ]
// All GEMM jobs are 128x128 tiles, BK=64, dbuf LDS, early-issue
// global_load_lds w16, XOR-chunk swizzle (0 bank conflicts), per-job
// bijective XCD swizzle (job sizes are multiples of 8).

#define B_ 64
#define T_ 200
#define I_ 512
#define H_ 2048
#define O_ 512
#define BH_ 131072
#define DELAY_ 20
#define DT_ 0.05f
#define RMEM_ 0.1f

typedef __bf16 bf16x8 __attribute__((ext_vector_type(8)));
typedef float f32x4 __attribute__((ext_vector_type(4)));

__device__ __forceinline__ unsigned short f2bf(float f) {
    unsigned int u = __builtin_bit_cast(unsigned int, f);
    u = (u + 0x7fff + ((u >> 16) & 1)) >> 16;
    return (unsigned short)u;
}
__device__ __forceinline__ float bf2f(unsigned short u) {
    return __builtin_bit_cast(float, (unsigned int)u << 16);
}

__device__ __forceinline__ void gload16(const void* g, void* l) {
    __builtin_amdgcn_global_load_lds(
        (const __attribute__((address_space(1))) unsigned int*)g,
        (__attribute__((address_space(3))) unsigned int*)l, 16, 0, 0);
}

// ---------- f32 -> bf16 (same layout) ----------
__global__ void k_cvt4(const float* __restrict__ in, unsigned short* __restrict__ out, int n4) {
    int i = blockIdx.x * 256 + threadIdx.x;
    if (i >= n4) return;
    float4 v = ((const float4*)in)[i];
    ushort4 o;
    o.x = f2bf(v.x); o.y = f2bf(v.y); o.z = f2bf(v.z); o.w = f2bf(v.w);
    ((ushort4*)out)[i] = o;
}

// ---------- f32 (R x C) -> bf16 transposed (C x R), 32x32 LDS tiles ----------
__global__ __launch_bounds__(256) void k_tcvt(const float* __restrict__ in,
                                              unsigned short* __restrict__ out, int R, int C) {
    __shared__ float t[32][33];
    int bx = blockIdx.x, by = blockIdx.y;
    int tx = threadIdx.x & 31, ty = threadIdx.x >> 5;
    #pragma unroll
    for (int r = 0; r < 32; r += 8)
        t[ty + r][tx] = in[(size_t)(by * 32 + ty + r) * C + bx * 32 + tx];
    __syncthreads();
    #pragma unroll
    for (int r = 0; r < 32; r += 8)
        out[(size_t)(bx * 32 + ty + r) * R + by * 32 + tx] = f2bf(t[tx][ty + r]);
}

// ---------- multi-job bf16 GEMM, 128x128 tiles ----------
// amap==1: A row m -> x row (m&63)*200 + (m>>6) + aoff
// cmap==1: C row m -> out row (m&63)*200 + (m>>6) + coff
// cbf16: C is bf16 (beta supported); else f32 (+bias).
struct Job {
    const unsigned short* A;
    const unsigned short* Bt;
    void* C;
    const float* bias;
    int kfull, lda, ldb, ldc;
    int amap, aoff, cmap, coff;
    int cbf16, beta, gx, gy;
};
struct MArgs { Job j[3]; int c1, c2, c3; };

__global__ __launch_bounds__(256) void k_mgemm(MArgs a) {
    __shared__ unsigned short As[2 * 128 * 64];
    __shared__ unsigned short Bs[2 * 128 * 64];

    const int hw = blockIdx.x;
    const int ji = (hw >= a.c1) + (hw >= a.c2);
    Job J; int jb, nb;
    if (ji == 0)      { J = a.j[0]; jb = 0;    nb = a.c1; }
    else if (ji == 1) { J = a.j[1]; jb = a.c1; nb = a.c2 - a.c1; }
    else              { J = a.j[2]; jb = a.c2; nb = a.c3 - a.c2; }
    const int lb = hw - jb;                       // job bases are %8==0
    const int wid = (lb & 7) * (nb >> 3) + (lb >> 3);
    int bm, bn;
    if (J.gx <= J.gy) { bn = wid % J.gx; bm = wid / J.gx; }
    else              { bm = wid % J.gy; bn = wid / J.gy; }

    const int tid = threadIdx.x;
    const int lane = tid & 63, wave = tid >> 6;
    const int wr = (wave >> 1) * 64, wc = (wave & 1) * 64;
    const int fr = lane & 15, kg = lane >> 4;
    const int rx = fr & 7;

    // staging: slot s = (row, cp); global chunk cg = cp ^ (row&7)
    const unsigned short* Ap[4]; const unsigned short* Bp[4]; int ls[4];
    #pragma unroll
    for (int it = 0; it < 4; ++it) {
        int s = tid + it * 256;
        int row = s >> 3, cp = s & 7, cg = cp ^ (row & 7);
        int gm = bm * 128 + row;
        int ar = J.amap ? ((gm & 63) * 200 + (gm >> 6) + J.aoff) : gm;
        Ap[it] = J.A + (size_t)ar * J.lda + cg * 8;
        Bp[it] = J.Bt + (size_t)(bn * 128 + row) * J.ldb + cg * 8;
        ls[it] = s * 8;
    }

    auto stage = [&](int buf, int kt) {
        const int ko = kt * 64;
        #pragma unroll
        for (int it = 0; it < 4; ++it) {
            gload16(Ap[it] + ko, &As[buf * 8192 + ls[it]]);
            gload16(Bp[it] + ko, &Bs[buf * 8192 + ls[it]]);
        }
    };

    f32x4 acc[4][4] = {};
    const int nk = J.kfull >> 6;

    stage(0, 0);
    __syncthreads();
    for (int kt = 0; kt < nk; ++kt) {
        const int cur = kt & 1;
        if (kt + 1 < nk) stage(cur ^ 1, kt + 1);   // issue next-tile loads first
        #pragma unroll
        for (int kk = 0; kk < 2; ++kk) {
            const int ck = (kk << 2) | kg;
            bf16x8 af[4], bfr[4];
            #pragma unroll
            for (int i = 0; i < 4; ++i) {
                af[i]  = *(const bf16x8*)(&As[cur * 8192 + (wr + i * 16 + fr) * 64 + ((ck ^ rx) << 3)]);
                bfr[i] = *(const bf16x8*)(&Bs[cur * 8192 + (wc + i * 16 + fr) * 64 + ((ck ^ rx) << 3)]);
            }
            #pragma unroll
            for (int i = 0; i < 4; ++i)
                #pragma unroll
                for (int j = 0; j < 4; ++j)
                    acc[i][j] = __builtin_amdgcn_mfma_f32_16x16x32_bf16(af[i], bfr[j], acc[i][j], 0, 0, 0);
        }
        __syncthreads();
    }

    #pragma unroll
    for (int i = 0; i < 4; ++i) {
        int rbase = bm * 128 + wr + i * 16 + kg * 4;
        #pragma unroll
        for (int j = 0; j < 4; ++j) {
            int col = bn * 128 + wc + j * 16 + fr;
            #pragma unroll
            for (int r = 0; r < 4; ++r) {
                int m = rbase + r;
                int cr = J.cmap ? ((m & 63) * 200 + (m >> 6) + J.coff) : m;
                size_t off = (size_t)cr * J.ldc + col;
                float v = acc[i][j][r];
                if (J.cbf16) {
                    unsigned short* Cb = (unsigned short*)J.C;
                    if (J.beta) v += bf2f(Cb[off]);
                    Cb[off] = f2bf(v);
                } else {
                    float* Cf = (float*)J.C;
                    if (J.bias) v += J.bias[col];
                    Cf[off] = v;
                }
            }
        }
    }
}

// ---------- per-(b,h) recurrence, 4 neurons/thread, one chunk ----------
__global__ __launch_bounds__(256) void k_rec(
    const unsigned short* __restrict__ S, unsigned short* __restrict__ F,
    float* __restrict__ volt, float* __restrict__ fire, float* __restrict__ asc,
    const float* __restrict__ thresh, const float* __restrict__ km,
    const float* __restrict__ asc_amp, const float* __restrict__ asc_r,
    const float* __restrict__ asc_k, int t0)
{
    int base = (blockIdx.x * 256 + threadIdx.x) * 4;
    int h = base & (H_ - 1);
    float v[4], f[4], a0[4], a1[4], th[4], dtk[4], amp0[4], amp1[4], r0[4], r1[4], d0[4], d1[4];
    *(float4*)v  = *(const float4*)(volt + base);
    *(float4*)f  = *(const float4*)(fire + base);
    *(float4*)a0 = *(const float4*)(asc + base);
    *(float4*)a1 = *(const float4*)(asc + BH_ + base);
    *(float4*)th = *(const float4*)(thresh + h);
    *(float4*)amp0 = *(const float4*)(asc_amp + h);
    *(float4*)amp1 = *(const float4*)(asc_amp + H_ + h);
    *(float4*)r0 = *(const float4*)(asc_r + h);
    *(float4*)r1 = *(const float4*)(asc_r + H_ + h);
    #pragma unroll
    for (int q = 0; q < 4; ++q) {
        dtk[q] = DT_ * km[h + q];
        d0[q] = expf(-DT_ * asc_k[h + q]);
        d1[q] = expf(-DT_ * asc_k[H_ + h + q]);
    }
    for (int t = 0; t < DELAY_; ++t) {
        ushort4 s4 = *(const ushort4*)(S + (size_t)(t0 + t) * BH_ + base);
        ushort4 o4;
        unsigned short* sp = (unsigned short*)&s4;
        unsigned short* op = (unsigned short*)&o4;
        #pragma unroll
        for (int q = 0; q < 4; ++q) {
            float syn = bf2f(sp[q]);
            float na0 = a0[q] * d0[q] + f[q] * (r0[q] * a0[q] + amp0[q]);
            float na1 = a1[q] * d1[q] + f[q] * (r1[q] * a1[q] + amp1[q]);
            a0[q] = na0; a1[q] = na1;
            float tot = syn + a0[q] + a1[q];
            v[q] = v[q] * (1.f - f[q]);
            v[q] = v[q] + dtk[q] * (RMEM_ * tot - v[q]);
            f[q] = 1.f / (1.f + expf(-(v[q] - th[q])));
            op[q] = f2bf(f[q]);
        }
        *(ushort4*)(F + (size_t)(t0 + t) * BH_ + base) = o4;
    }
    *(float4*)(volt + base) = *(float4*)v;
    *(float4*)(fire + base) = *(float4*)f;
    *(float4*)(asc + base) = *(float4*)a0;
    *(float4*)(asc + BH_ + base) = *(float4*)a1;
}

extern "C" void kernel_launch(void* const* d_in, const int* in_sizes, int n_in,
                              void* d_out, int out_size, void* d_ws, size_t ws_size,
                              hipStream_t stream) {
    const float* x       = (const float*)d_in[0];
    const float* w_iv    = (const float*)d_in[1];
    const float* w_lat   = (const float*)d_in[2];
    const float* thresh  = (const float*)d_in[3];
    const float* km      = (const float*)d_in[4];
    const float* asc_amp = (const float*)d_in[5];
    const float* asc_r   = (const float*)d_in[6];
    const float* asc_k   = (const float*)d_in[7];
    const float* w_out   = (const float*)d_in[8];
    const float* b_out   = (const float*)d_in[9];
    float* out = (float*)d_out;

    char* ws = (char*)d_ws;
    unsigned short* Sb    = (unsigned short*)ws;                          // 52,428,800 (T,B,H) bf16
    unsigned short* Fb    = (unsigned short*)(ws + 52428800);             // 52,428,800 (T,B,H) bf16
    unsigned short* xb    = (unsigned short*)(ws + 104857600);            // 13,107,200
    unsigned short* WivT  = (unsigned short*)(ws + 117964800);            //  2,097,152 (H,I)
    unsigned short* WlatT = (unsigned short*)(ws + 120061952);            //  8,388,608 (H,H)
    unsigned short* WoutT = (unsigned short*)(ws + 128450560);            //  2,097,152 (O,H)
    float*          volt  = (float*)(ws + 130547712);
    float*          fire  = (float*)(ws + 131072000);
    float*          asc   = (float*)(ws + 131596288);                     // 2*BH f32

    k_cvt4<<<6400, 256, 0, stream>>>(x, xb, (B_ * T_ * I_) / 4);
    k_tcvt<<<dim3(H_ / 32, I_ / 32), 256, 0, stream>>>(w_iv, WivT, I_, H_);
    k_tcvt<<<dim3(H_ / 32, H_ / 32), 256, 0, stream>>>(w_lat, WlatT, H_, H_);
    k_tcvt<<<dim3(O_ / 32, H_ / 32), 256, 0, stream>>>(w_out, WoutT, H_, O_);
    hipMemsetAsync(volt, 0, 524288 + 524288 + 1048576, stream);

    // job builders (all 128x128 tiles)
    auto sffJob = [&](int ci) {
        Job j; j.A = xb; j.Bt = WivT; j.C = Sb + (size_t)ci * DELAY_ * BH_; j.bias = nullptr;
        j.kfull = I_; j.lda = I_; j.ldb = I_; j.ldc = H_;
        j.amap = 1; j.aoff = ci * DELAY_; j.cmap = 0; j.coff = 0;
        j.cbf16 = 1; j.beta = 0; j.gx = H_ / 128; j.gy = DELAY_ * B_ / 128;   // 160 blocks
        return j;
    };
    auto latJob = [&](int c) {
        Job j; j.A = Fb + (size_t)(c - 1) * DELAY_ * BH_; j.Bt = WlatT;
        j.C = Sb + (size_t)c * DELAY_ * BH_; j.bias = nullptr;
        j.kfull = H_; j.lda = H_; j.ldb = H_; j.ldc = H_;
        j.amap = 0; j.aoff = 0; j.cmap = 0; j.coff = 0;
        j.cbf16 = 1; j.beta = 1; j.gx = H_ / 128; j.gy = DELAY_ * B_ / 128;   // 160 blocks
        return j;
    };
    auto outJob = [&](int c) {
        Job j; j.A = Fb + (size_t)c * DELAY_ * BH_; j.Bt = WoutT; j.C = out; j.bias = b_out;
        j.kfull = H_; j.lda = H_; j.ldb = H_; j.ldc = O_;
        j.amap = 0; j.aoff = 0; j.cmap = 1; j.coff = c * DELAY_;
        j.cbf16 = 0; j.beta = 0; j.gx = O_ / 128; j.gy = DELAY_ * B_ / 128;   // 40 blocks
        return j;
    };
    auto launch = [&](Job j0, int n0, Job j1, int n1, Job j2, int n2) {
        MArgs a; a.j[0] = j0; a.j[1] = n1 ? j1 : j0; a.j[2] = n2 ? j2 : j0;
        a.c1 = n0; a.c2 = n0 + n1; a.c3 = n0 + n1 + n2;
        k_mgemm<<<a.c3, 256, 0, stream>>>(a);
    };
    auto rec = [&](int c) {
        k_rec<<<BH_ / 1024, 256, 0, stream>>>(Sb, Fb, volt, fire, asc,
                                              thresh, km, asc_amp, asc_r, asc_k, c * DELAY_);
    };

    // D0: feed-forward for chunks 0 and 1
    launch(sffJob(0), 160, sffJob(1), 160, sffJob(0), 0);
    rec(0);
    for (int c = 1; c < T_ / DELAY_; ++c) {
        if (c <= 8) launch(latJob(c), 160, outJob(c - 1), 40, sffJob(c + 1), 160);
        else        launch(latJob(c), 160, outJob(c - 1), 40, latJob(c), 0);
        rec(c);
    }
    launch(outJob(9), 40, outJob(9), 0, outJob(9), 0);
}

// Round 7
// 510.232 us; speedup vs baseline: 1.2848x; 1.2848x over previous
//
#include <hip/hip_runtime.h>
#include <hip/hip_bf16.h>

// GLIFR forward, MI355X.
//   Sb(T,B,H) bf16 = x @ W_iv              (GEMM <64,128>, 3200 blocks)
//   for chunk c in 0..9 (20 steps == DELAY):
//     if c>0: Sb[c] += F[c-1] @ W_lat      (GEMM <64,64>, 640 blocks, beta bf16)
//     k_rec: ASC/volt/firing x20 -> F bf16
//   out(B,T,O) f32 = F @ w_out + b_out     (GEMM <64,128>, 800 blocks)
// GEMM: 3-stage LDS rotation, counted s_waitcnt vmcnt(LPS) (T4 — loads stay
// in flight across barriers), global_load_lds w16, XOR-chunk swizzle
// (0 bank conflicts), bijective XCD block swizzle.

#define B_ 64
#define T_ 200
#define I_ 512
#define H_ 2048
#define O_ 512
#define BH_ 131072
#define DELAY_ 20
#define DT_ 0.05f
#define RMEM_ 0.1f

typedef __bf16 bf16x8 __attribute__((ext_vector_type(8)));
typedef float f32x4 __attribute__((ext_vector_type(4)));

__device__ __forceinline__ unsigned short f2bf(float f) {
    unsigned int u = __builtin_bit_cast(unsigned int, f);
    u = (u + 0x7fff + ((u >> 16) & 1)) >> 16;
    return (unsigned short)u;
}
__device__ __forceinline__ float bf2f(unsigned short u) {
    return __builtin_bit_cast(float, (unsigned int)u << 16);
}

__device__ __forceinline__ void gload16(const void* g, void* l) {
    __builtin_amdgcn_global_load_lds(
        (const __attribute__((address_space(1))) unsigned int*)g,
        (__attribute__((address_space(3))) unsigned int*)l, 16, 0, 0);
}

// ---------- f32 -> bf16 (same layout) ----------
__global__ void k_cvt4(const float* __restrict__ in, unsigned short* __restrict__ out, int n4) {
    int i = blockIdx.x * 256 + threadIdx.x;
    if (i >= n4) return;
    float4 v = ((const float4*)in)[i];
    ushort4 o;
    o.x = f2bf(v.x); o.y = f2bf(v.y); o.z = f2bf(v.z); o.w = f2bf(v.w);
    ((ushort4*)out)[i] = o;
}

// ---------- f32 (R x C) -> bf16 transposed (C x R), 32x32 LDS tiles ----------
__global__ __launch_bounds__(256) void k_tcvt(const float* __restrict__ in,
                                              unsigned short* __restrict__ out, int R, int C) {
    __shared__ float t[32][33];
    int bx = blockIdx.x, by = blockIdx.y;
    int tx = threadIdx.x & 31, ty = threadIdx.x >> 5;
    #pragma unroll
    for (int r = 0; r < 32; r += 8)
        t[ty + r][tx] = in[(size_t)(by * 32 + ty + r) * C + bx * 32 + tx];
    __syncthreads();
    #pragma unroll
    for (int r = 0; r < 32; r += 8)
        out[(size_t)(bx * 32 + ty + r) * R + by * 32 + tx] = f2bf(t[tx][ty + r]);
}

// ---------- bf16 GEMM: C(MxN) = [C +] A(MxK) * Bt(NxK)^T [+ bias] ----------
// amap/cmap==1: m -> (m&63)*200 + (m>>6)   ((t,b) row <-> (b,t) row)
// 3-stage LDS rotation + counted vmcnt. Requires K/64 (nk) >= 2.
template<int BM, int BN>
__global__ __launch_bounds__(256) void k_gemm(
    const unsigned short* __restrict__ A, const unsigned short* __restrict__ Bt,
    void* __restrict__ Cv, const float* __restrict__ bias,
    int K, int lda, int ldb, int ldc, int amap, int cmap, int cbf16, int beta,
    int gx, int gy)
{
    constexpr int AIT = BM / 32, BIT = BN / 32;   // 16B gloads per thread per stage
    constexpr int LPS = AIT + BIT;                // loads per stage (per thread)
    constexpr int ASZ = BM * 64, BSZ = BN * 64;   // shorts per stage
    constexpr int WTM = BM / 2, WTN = BN / 2;     // 2x2 wave grid
    constexpr int FM = WTM / 16, FN = WTN / 16;
    __shared__ unsigned short As[3 * ASZ];
    __shared__ unsigned short Bs[3 * BSZ];

    const int nb = gx * gy;
    const int hw = blockIdx.x;
    const int wid = (hw & 7) * (nb >> 3) + (hw >> 3);
    int bm, bn;
    if (gx <= gy) { bn = wid % gx; bm = wid / gx; }
    else          { bm = wid % gy; bn = wid / gy; }

    const int tid = threadIdx.x;
    const int lane = tid & 63, wave = tid >> 6;
    const int wr = (wave >> 1) * WTM, wc = (wave & 1) * WTN;
    const int fr = lane & 15, kg = lane >> 4;
    const int rx = fr & 7;

    // staging source pointers: slot s = (row, cp); global chunk cg = cp^(row&7)
    const unsigned short* Ap[AIT]; int lsA[AIT];
    #pragma unroll
    for (int it = 0; it < AIT; ++it) {
        int s = tid + it * 256;
        int row = s >> 3, cp = s & 7, cg = cp ^ (row & 7);
        int gm = bm * BM + row;
        int ar = amap ? ((gm & 63) * 200 + (gm >> 6)) : gm;
        Ap[it] = A + (size_t)ar * lda + cg * 8;
        lsA[it] = s * 8;
    }
    const unsigned short* Bp[BIT]; int lsB[BIT];
    #pragma unroll
    for (int it = 0; it < BIT; ++it) {
        int s = tid + it * 256;
        int row = s >> 3, cp = s & 7, cg = cp ^ (row & 7);
        Bp[it] = Bt + (size_t)(bn * BN + row) * ldb + cg * 8;
        lsB[it] = s * 8;
    }

    auto stage = [&](int buf, int kt) {
        const int ko = kt * 64;
        #pragma unroll
        for (int it = 0; it < AIT; ++it)
            gload16(Ap[it] + ko, &As[buf * ASZ + lsA[it]]);
        #pragma unroll
        for (int it = 0; it < BIT; ++it)
            gload16(Bp[it] + ko, &Bs[buf * BSZ + lsB[it]]);
    };

    f32x4 acc[FM][FN] = {};
    const int nk = K >> 6;

    stage(0, 0);
    stage(1, 1);
    for (int t = 0; t < nk; ++t) {
        // wait: all stages except the newest (t+1) have landed; own ds_reads done
        if (t == nk - 1) {
            asm volatile("s_waitcnt vmcnt(0) lgkmcnt(0)" ::: "memory");
        } else {
            asm volatile("s_waitcnt vmcnt(%0) lgkmcnt(0)" :: "n"(LPS) : "memory");
        }
        __builtin_amdgcn_s_barrier();
        if (t + 2 < nk) stage((t + 2) % 3, t + 2);   // overwrites buf read 2 iters ago
        const int cur = t % 3;
        #pragma unroll
        for (int kk = 0; kk < 2; ++kk) {
            const int ck = (kk << 2) | kg;
            bf16x8 af[FM], bfr[FN];
            #pragma unroll
            for (int i = 0; i < FM; ++i)
                af[i] = *(const bf16x8*)(&As[cur * ASZ + (wr + i * 16 + fr) * 64 + ((ck ^ rx) << 3)]);
            #pragma unroll
            for (int j = 0; j < FN; ++j)
                bfr[j] = *(const bf16x8*)(&Bs[cur * BSZ + (wc + j * 16 + fr) * 64 + ((ck ^ rx) << 3)]);
            #pragma unroll
            for (int i = 0; i < FM; ++i)
                #pragma unroll
                for (int j = 0; j < FN; ++j)
                    acc[i][j] = __builtin_amdgcn_mfma_f32_16x16x32_bf16(af[i], bfr[j], acc[i][j], 0, 0, 0);
        }
    }

    #pragma unroll
    for (int i = 0; i < FM; ++i) {
        int rbase = bm * BM + wr + i * 16 + kg * 4;
        #pragma unroll
        for (int j = 0; j < FN; ++j) {
            int col = bn * BN + wc + j * 16 + fr;
            #pragma unroll
            for (int r = 0; r < 4; ++r) {
                int m = rbase + r;
                int cr = cmap ? ((m & 63) * 200 + (m >> 6)) : m;
                size_t off = (size_t)cr * ldc + col;
                float v = acc[i][j][r];
                if (cbf16) {
                    unsigned short* Cb = (unsigned short*)Cv;
                    if (beta) v += bf2f(Cb[off]);
                    Cb[off] = f2bf(v);
                } else {
                    float* Cf = (float*)Cv;
                    if (bias) v += bias[col];
                    Cf[off] = v;
                }
            }
        }
    }
}

// ---------- per-(b,h) recurrence, 4 neurons/thread, one chunk ----------
__global__ __launch_bounds__(256) void k_rec(
    const unsigned short* __restrict__ S, unsigned short* __restrict__ F,
    float* __restrict__ volt, float* __restrict__ fire, float* __restrict__ asc,
    const float* __restrict__ thresh, const float* __restrict__ km,
    const float* __restrict__ asc_amp, const float* __restrict__ asc_r,
    const float* __restrict__ asc_k, int t0)
{
    int base = (blockIdx.x * 256 + threadIdx.x) * 4;
    int h = base & (H_ - 1);
    float v[4], f[4], a0[4], a1[4], th[4], dtk[4], amp0[4], amp1[4], r0[4], r1[4], d0[4], d1[4];
    *(float4*)v  = *(const float4*)(volt + base);
    *(float4*)f  = *(const float4*)(fire + base);
    *(float4*)a0 = *(const float4*)(asc + base);
    *(float4*)a1 = *(const float4*)(asc + BH_ + base);
    *(float4*)th = *(const float4*)(thresh + h);
    *(float4*)amp0 = *(const float4*)(asc_amp + h);
    *(float4*)amp1 = *(const float4*)(asc_amp + H_ + h);
    *(float4*)r0 = *(const float4*)(asc_r + h);
    *(float4*)r1 = *(const float4*)(asc_r + H_ + h);
    #pragma unroll
    for (int q = 0; q < 4; ++q) {
        dtk[q] = DT_ * km[h + q];
        d0[q] = expf(-DT_ * asc_k[h + q]);
        d1[q] = expf(-DT_ * asc_k[H_ + h + q]);
    }
    for (int t = 0; t < DELAY_; ++t) {
        ushort4 s4 = *(const ushort4*)(S + (size_t)(t0 + t) * BH_ + base);
        ushort4 o4;
        unsigned short* sp = (unsigned short*)&s4;
        unsigned short* op = (unsigned short*)&o4;
        #pragma unroll
        for (int q = 0; q < 4; ++q) {
            float syn = bf2f(sp[q]);
            float na0 = a0[q] * d0[q] + f[q] * (r0[q] * a0[q] + amp0[q]);
            float na1 = a1[q] * d1[q] + f[q] * (r1[q] * a1[q] + amp1[q]);
            a0[q] = na0; a1[q] = na1;
            float tot = syn + a0[q] + a1[q];
            v[q] = v[q] * (1.f - f[q]);
            v[q] = v[q] + dtk[q] * (RMEM_ * tot - v[q]);
            f[q] = 1.f / (1.f + expf(-(v[q] - th[q])));
            op[q] = f2bf(f[q]);
        }
        *(ushort4*)(F + (size_t)(t0 + t) * BH_ + base) = o4;
    }
    *(float4*)(volt + base) = *(float4*)v;
    *(float4*)(fire + base) = *(float4*)f;
    *(float4*)(asc + base) = *(float4*)a0;
    *(float4*)(asc + BH_ + base) = *(float4*)a1;
}

extern "C" void kernel_launch(void* const* d_in, const int* in_sizes, int n_in,
                              void* d_out, int out_size, void* d_ws, size_t ws_size,
                              hipStream_t stream) {
    const float* x       = (const float*)d_in[0];
    const float* w_iv    = (const float*)d_in[1];
    const float* w_lat   = (const float*)d_in[2];
    const float* thresh  = (const float*)d_in[3];
    const float* km      = (const float*)d_in[4];
    const float* asc_amp = (const float*)d_in[5];
    const float* asc_r   = (const float*)d_in[6];
    const float* asc_k   = (const float*)d_in[7];
    const float* w_out   = (const float*)d_in[8];
    const float* b_out   = (const float*)d_in[9];
    float* out = (float*)d_out;

    char* ws = (char*)d_ws;
    unsigned short* Sb    = (unsigned short*)ws;                          // 52,428,800 (T,B,H) bf16
    unsigned short* Fb    = (unsigned short*)(ws + 52428800);             // 52,428,800 (T,B,H) bf16
    unsigned short* xb    = (unsigned short*)(ws + 104857600);            // 13,107,200
    unsigned short* WivT  = (unsigned short*)(ws + 117964800);            //  2,097,152 (H,I)
    unsigned short* WlatT = (unsigned short*)(ws + 120061952);            //  8,388,608 (H,H)
    unsigned short* WoutT = (unsigned short*)(ws + 128450560);            //  2,097,152 (O,H)
    float*          volt  = (float*)(ws + 130547712);
    float*          fire  = (float*)(ws + 131072000);
    float*          asc   = (float*)(ws + 131596288);                     // 2*BH f32

    k_cvt4<<<6400, 256, 0, stream>>>(x, xb, (B_ * T_ * I_) / 4);
    k_tcvt<<<dim3(H_ / 32, I_ / 32), 256, 0, stream>>>(w_iv, WivT, I_, H_);
    k_tcvt<<<dim3(H_ / 32, H_ / 32), 256, 0, stream>>>(w_lat, WlatT, H_, H_);
    k_tcvt<<<dim3(O_ / 32, H_ / 32), 256, 0, stream>>>(w_out, WoutT, H_, O_);
    hipMemsetAsync(volt, 0, 524288 + 524288 + 1048576, stream);

    // Sb = x @ W_iv : <64,128>, 200x16 = 3200 blocks, bf16 out, A rows gathered
    k_gemm<64, 128><<<(B_ * T_ / 64) * (H_ / 128), 256, 0, stream>>>(
        xb, WivT, Sb, nullptr, I_, I_, I_, H_, 1, 0, 1, 0, H_ / 128, B_ * T_ / 64);

    for (int c = 0; c < T_ / DELAY_; ++c) {
        if (c) {
            // Sb[c] += F[c-1] @ W_lat : <64,64>, 20x32 = 640 blocks, beta bf16
            k_gemm<64, 64><<<(DELAY_ * B_ / 64) * (H_ / 64), 256, 0, stream>>>(
                Fb + (size_t)(c - 1) * DELAY_ * BH_, WlatT,
                Sb + (size_t)c * DELAY_ * BH_, nullptr,
                H_, H_, H_, H_, 0, 0, 1, 1, H_ / 64, DELAY_ * B_ / 64);
        }
        k_rec<<<BH_ / 1024, 256, 0, stream>>>(Sb, Fb, volt, fire, asc,
                                              thresh, km, asc_amp, asc_r, asc_k,
                                              c * DELAY_);
    }

    // out = F @ w_out + b_out : <64,128>, 200x4 = 800 blocks, f32 out, cmap
    k_gemm<64, 128><<<(B_ * T_ / 64) * (O_ / 128), 256, 0, stream>>>(
        Fb, WoutT, out, b_out, H_, H_, H_, O_, 0, 1, 0, 0, O_ / 128, B_ * T_ / 64);
}

// Round 8
// 437.384 us; speedup vs baseline: 1.4988x; 1.1666x over previous
//
#include <hip/hip_runtime.h>
#include <hip/hip_bf16.h>

// GLIFR forward, MI355X.
//   xbt = x transposed to (t*64+b) rows, bf16. WcatT = [W_lat ; W_iv]^T (rows N=H, K=2560).
//   chunk 0: P0 = x_0 @ W_iv                     (GEMM <64,64>, 640 blocks, K=512)
//   chunk c>=1: {P0,P1} = [F[c-1] | x_c] @ Wcat  (GEMM <128,64>, split-K=2, 640 blocks, K=2560)
//   k_rec: syn = P0 (+P1); ASC/volt/firing x20 -> F bf16
//   out(B,T,O) f32 = F @ w_out + b_out           (GEMM <128,128>, 400 blocks)
// GEMM: 2-stage dbuf LDS, early-issue global_load_lds w16, XOR-chunk swizzle
// (0 bank conflicts), bijective XCD block swizzle, split-K via separate bf16
// partial buffers summed by k_rec.

#define B_ 64
#define T_ 200
#define I_ 512
#define H_ 2048
#define O_ 512
#define BH_ 131072
#define DELAY_ 20
#define DT_ 0.05f
#define RMEM_ 0.1f

typedef __bf16 bf16x8 __attribute__((ext_vector_type(8)));
typedef float f32x4 __attribute__((ext_vector_type(4)));

__device__ __forceinline__ unsigned short f2bf(float f) {
    unsigned int u = __builtin_bit_cast(unsigned int, f);
    u = (u + 0x7fff + ((u >> 16) & 1)) >> 16;
    return (unsigned short)u;
}
__device__ __forceinline__ float bf2f(unsigned short u) {
    return __builtin_bit_cast(float, (unsigned int)u << 16);
}

__device__ __forceinline__ void gload16(const void* g, void* l) {
    __builtin_amdgcn_global_load_lds(
        (const __attribute__((address_space(1))) unsigned int*)g,
        (__attribute__((address_space(3))) unsigned int*)l, 16, 0, 0);
}

// ---------- x (B,T,I) f32 -> xbt rows (t*64+b) x I, bf16 ----------
__global__ void k_cvt_tb(const float* __restrict__ in, unsigned short* __restrict__ out) {
    int g = blockIdx.x * 256 + threadIdx.x;        // 4-elem group
    int idx = g * 4;
    int r = idx >> 9;                              // out row (t*64+b)
    int i0 = idx & 511;
    int t = r >> 6, b = r & 63;
    float4 v = *(const float4*)(in + ((size_t)b * T_ + t) * I_ + i0);
    ushort4 o;
    o.x = f2bf(v.x); o.y = f2bf(v.y); o.z = f2bf(v.z); o.w = f2bf(v.w);
    *(ushort4*)(out + idx) = o;
}

// ---------- f32 (R x C) -> bf16 transposed rows C x (ldo), at col ooff ----------
__global__ __launch_bounds__(256) void k_tcvt(const float* __restrict__ in,
                                              unsigned short* __restrict__ out,
                                              int R, int C, int ldo, int ooff) {
    __shared__ float t[32][33];
    int bx = blockIdx.x, by = blockIdx.y;
    int tx = threadIdx.x & 31, ty = threadIdx.x >> 5;
    #pragma unroll
    for (int r = 0; r < 32; r += 8)
        t[ty + r][tx] = in[(size_t)(by * 32 + ty + r) * C + bx * 32 + tx];
    __syncthreads();
    #pragma unroll
    for (int r = 0; r < 32; r += 8)
        out[(size_t)(bx * 32 + ty + r) * ldo + ooff + by * 32 + tx] = f2bf(t[tx][ty + r]);
}

// ---------- bf16 GEMM: C = A(M x K) * Bt(N x K)^T ----------
// A is split along K: cols [0,k1) from A1 (lda1), [k1,K) from A2 (lda2).
// B element (n,k) = Bt[n*ldbt + kboff + k].
// ksplit: block computes K-slice and writes bf16 partial C + split*csplit.
// cbf16==0: f32 out (+bias), cmap: row m -> (m&63)*200 + (m>>6).
template<int BM, int BN>
__global__ __launch_bounds__(256) void k_gemm(
    const unsigned short* __restrict__ A1, const unsigned short* __restrict__ A2,
    const unsigned short* __restrict__ Bt, void* __restrict__ Cv,
    const float* __restrict__ bias,
    int k1, int K, int lda1, int lda2, int ldbt, int kboff, int ldc,
    int cmap, int cbf16, int ksplit, long long csplit, int gx, int gy)
{
    constexpr int AIT = BM / 32, BIT = BN / 32;
    constexpr int ASZ = BM * 64, BSZ = BN * 64;
    constexpr int WTM = BM / 2, WTN = BN / 2;
    constexpr int FM = WTM / 16, FN = WTN / 16;
    __shared__ unsigned short As[2 * ASZ];
    __shared__ unsigned short Bs[2 * BSZ];

    const int nb = gx * gy * ksplit;
    const int hw = blockIdx.x;
    const int wid = (hw & 7) * (nb >> 3) + (hw >> 3);
    const int layer = gx * gy;
    const int split = wid / layer;
    const int w2 = wid % layer;
    int bm, bn;
    if (gx <= gy) { bn = w2 % gx; bm = w2 / gx; }
    else          { bm = w2 % gy; bn = w2 / gy; }

    const int klen = K / ksplit;
    const int nk = klen >> 6;
    const int kb = (split * klen) >> 6;     // base k-tile

    const int tid = threadIdx.x;
    const int lane = tid & 63, wave = tid >> 6;
    const int wr = (wave >> 1) * WTM, wc = (wave & 1) * WTN;
    const int fr = lane & 15, kg = lane >> 4;
    const int rx = fr & 7;

    // staging: slot s = (row, cp); global chunk cg = cp ^ (row&7)
    int arow[AIT], acg[AIT], lsA[AIT];
    #pragma unroll
    for (int it = 0; it < AIT; ++it) {
        int s = tid + it * 256;
        int row = s >> 3, cp = s & 7;
        acg[it] = (cp ^ (row & 7)) * 8;
        arow[it] = bm * BM + row;
        lsA[it] = s * 8;
    }
    const unsigned short* Bp[BIT]; int lsB[BIT];
    #pragma unroll
    for (int it = 0; it < BIT; ++it) {
        int s = tid + it * 256;
        int row = s >> 3, cp = s & 7, cg = cp ^ (row & 7);
        Bp[it] = Bt + (size_t)(bn * BN + row) * ldbt + kboff + cg * 8;
        lsB[it] = s * 8;
    }

    auto stage = [&](int buf, int ktg) {
        const int kc = ktg << 6;
        #pragma unroll
        for (int it = 0; it < AIT; ++it) {
            int kcol = kc + acg[it];
            const unsigned short* p = (kcol < k1)
                ? A1 + (size_t)arow[it] * lda1 + kcol
                : A2 + (size_t)arow[it] * lda2 + (kcol - k1);
            gload16(p, &As[buf * ASZ + lsA[it]]);
        }
        #pragma unroll
        for (int it = 0; it < BIT; ++it)
            gload16(Bp[it] + kc, &Bs[buf * BSZ + lsB[it]]);
    };

    f32x4 acc[FM][FN] = {};

    stage(0, kb);
    __syncthreads();
    for (int t = 0; t < nk; ++t) {
        const int cur = t & 1;
        if (t + 1 < nk) stage(cur ^ 1, kb + t + 1);   // issue next-tile loads first
        #pragma unroll
        for (int kk = 0; kk < 2; ++kk) {
            const int ck = (kk << 2) | kg;
            bf16x8 af[FM], bfr[FN];
            #pragma unroll
            for (int i = 0; i < FM; ++i)
                af[i] = *(const bf16x8*)(&As[cur * ASZ + (wr + i * 16 + fr) * 64 + ((ck ^ rx) << 3)]);
            #pragma unroll
            for (int j = 0; j < FN; ++j)
                bfr[j] = *(const bf16x8*)(&Bs[cur * BSZ + (wc + j * 16 + fr) * 64 + ((ck ^ rx) << 3)]);
            #pragma unroll
            for (int i = 0; i < FM; ++i)
                #pragma unroll
                for (int j = 0; j < FN; ++j)
                    acc[i][j] = __builtin_amdgcn_mfma_f32_16x16x32_bf16(af[i], bfr[j], acc[i][j], 0, 0, 0);
        }
        __syncthreads();
    }

    #pragma unroll
    for (int i = 0; i < FM; ++i) {
        int rbase = bm * BM + wr + i * 16 + kg * 4;
        #pragma unroll
        for (int j = 0; j < FN; ++j) {
            int col = bn * BN + wc + j * 16 + fr;
            #pragma unroll
            for (int r = 0; r < 4; ++r) {
                int m = rbase + r;
                int cr = cmap ? ((m & 63) * 200 + (m >> 6)) : m;
                size_t off = (size_t)cr * ldc + col;
                float v = acc[i][j][r];
                if (cbf16) {
                    unsigned short* Cb = (unsigned short*)Cv + (size_t)split * csplit;
                    Cb[off] = f2bf(v);
                } else {
                    float* Cf = (float*)Cv;
                    if (bias) v += bias[col];
                    Cf[off] = v;
                }
            }
        }
    }
}

// ---------- per-(b,h) recurrence, 4 neurons/thread, one chunk ----------
// syn = P[0] (+ P[1] if nparts==2); P is chunk-local (DELAY x B x H) bf16.
__global__ __launch_bounds__(256) void k_rec(
    const unsigned short* __restrict__ P, int nparts, unsigned short* __restrict__ F,
    float* __restrict__ volt, float* __restrict__ fire, float* __restrict__ asc,
    const float* __restrict__ thresh, const float* __restrict__ km,
    const float* __restrict__ asc_amp, const float* __restrict__ asc_r,
    const float* __restrict__ asc_k, int t0)
{
    const size_t PSPL = (size_t)DELAY_ * BH_;
    int base = (blockIdx.x * 256 + threadIdx.x) * 4;
    int h = base & (H_ - 1);
    float v[4], f[4], a0[4], a1[4], th[4], dtk[4], amp0[4], amp1[4], r0[4], r1[4], d0[4], d1[4];
    *(float4*)v  = *(const float4*)(volt + base);
    *(float4*)f  = *(const float4*)(fire + base);
    *(float4*)a0 = *(const float4*)(asc + base);
    *(float4*)a1 = *(const float4*)(asc + BH_ + base);
    *(float4*)th = *(const float4*)(thresh + h);
    *(float4*)amp0 = *(const float4*)(asc_amp + h);
    *(float4*)amp1 = *(const float4*)(asc_amp + H_ + h);
    *(float4*)r0 = *(const float4*)(asc_r + h);
    *(float4*)r1 = *(const float4*)(asc_r + H_ + h);
    #pragma unroll
    for (int q = 0; q < 4; ++q) {
        dtk[q] = DT_ * km[h + q];
        d0[q] = expf(-DT_ * asc_k[h + q]);
        d1[q] = expf(-DT_ * asc_k[H_ + h + q]);
    }
    for (int t = 0; t < DELAY_; ++t) {
        ushort4 s4 = *(const ushort4*)(P + (size_t)t * BH_ + base);
        ushort4 s4b = s4;
        if (nparts == 2) s4b = *(const ushort4*)(P + PSPL + (size_t)t * BH_ + base);
        ushort4 o4;
        unsigned short* sp = (unsigned short*)&s4;
        unsigned short* sq = (unsigned short*)&s4b;
        unsigned short* op = (unsigned short*)&o4;
        #pragma unroll
        for (int q = 0; q < 4; ++q) {
            float syn = bf2f(sp[q]);
            if (nparts == 2) syn += bf2f(sq[q]);
            float na0 = a0[q] * d0[q] + f[q] * (r0[q] * a0[q] + amp0[q]);
            float na1 = a1[q] * d1[q] + f[q] * (r1[q] * a1[q] + amp1[q]);
            a0[q] = na0; a1[q] = na1;
            float tot = syn + a0[q] + a1[q];
            v[q] = v[q] * (1.f - f[q]);
            v[q] = v[q] + dtk[q] * (RMEM_ * tot - v[q]);
            f[q] = 1.f / (1.f + expf(-(v[q] - th[q])));
            op[q] = f2bf(f[q]);
        }
        *(ushort4*)(F + (size_t)(t0 + t) * BH_ + base) = o4;
    }
    *(float4*)(volt + base) = *(float4*)v;
    *(float4*)(fire + base) = *(float4*)f;
    *(float4*)(asc + base) = *(float4*)a0;
    *(float4*)(asc + BH_ + base) = *(float4*)a1;
}

extern "C" void kernel_launch(void* const* d_in, const int* in_sizes, int n_in,
                              void* d_out, int out_size, void* d_ws, size_t ws_size,
                              hipStream_t stream) {
    const float* x       = (const float*)d_in[0];
    const float* w_iv    = (const float*)d_in[1];
    const float* w_lat   = (const float*)d_in[2];
    const float* thresh  = (const float*)d_in[3];
    const float* km      = (const float*)d_in[4];
    const float* asc_amp = (const float*)d_in[5];
    const float* asc_r   = (const float*)d_in[6];
    const float* asc_k   = (const float*)d_in[7];
    const float* w_out   = (const float*)d_in[8];
    const float* b_out   = (const float*)d_in[9];
    float* out = (float*)d_out;

    char* ws = (char*)d_ws;
    unsigned short* P     = (unsigned short*)ws;                          // 10,485,760 (2 partials, DELAY*B*H bf16)
    unsigned short* Fb    = (unsigned short*)(ws + 10485760);             // 52,428,800 (T,B,H) bf16
    unsigned short* xbt   = (unsigned short*)(ws + 62914560);             // 13,107,200 (T*B rows x I) bf16
    unsigned short* WcatT = (unsigned short*)(ws + 76021760);             // 10,485,760 (H rows x 2560)
    unsigned short* WoutT = (unsigned short*)(ws + 86507520);             //  2,097,152 (O rows x H)
    float*          volt  = (float*)(ws + 88604672);
    float*          fire  = (float*)(ws + 89128960);
    float*          asc   = (float*)(ws + 89653248);                      // 2*BH f32

    k_cvt_tb<<<(T_ * B_ * I_ / 4) / 256, 256, 0, stream>>>(x, xbt);
    k_tcvt<<<dim3(H_ / 32, H_ / 32), 256, 0, stream>>>(w_lat, WcatT, H_, H_, 2560, 0);
    k_tcvt<<<dim3(H_ / 32, I_ / 32), 256, 0, stream>>>(w_iv, WcatT, I_, H_, 2560, 2048);
    k_tcvt<<<dim3(O_ / 32, H_ / 32), 256, 0, stream>>>(w_out, WoutT, H_, O_, 2048, 0);
    hipMemsetAsync(volt, 0, 524288 + 524288 + 1048576, stream);

    // chunk 0: P0 = x_0 @ W_iv  (K=512 via x-part of Wcat) : <64,64>, 640 blocks
    k_gemm<64, 64><<<(DELAY_ * B_ / 64) * (H_ / 64), 256, 0, stream>>>(
        nullptr, xbt, WcatT, P, nullptr,
        0, I_, 0, I_, 2560, 2048, H_, 0, 1, 1, 0, H_ / 64, DELAY_ * B_ / 64);
    k_rec<<<BH_ / 1024, 256, 0, stream>>>(P, 1, Fb, volt, fire, asc,
                                          thresh, km, asc_amp, asc_r, asc_k, 0);

    for (int c = 1; c < T_ / DELAY_; ++c) {
        // {P0,P1} = [F[c-1] | x_c] @ Wcat : <128,64>, split-K=2, 640 blocks
        k_gemm<128, 64><<<(DELAY_ * B_ / 128) * (H_ / 64) * 2, 256, 0, stream>>>(
            Fb + (size_t)(c - 1) * DELAY_ * BH_, xbt + (size_t)c * DELAY_ * B_ * I_,
            WcatT, P, nullptr,
            H_, H_ + I_, H_, I_, 2560, 0, H_, 0, 1, 2, (long long)DELAY_ * BH_,
            H_ / 64, DELAY_ * B_ / 128);
        k_rec<<<BH_ / 1024, 256, 0, stream>>>(P, 2, Fb, volt, fire, asc,
                                              thresh, km, asc_amp, asc_r, asc_k, c * DELAY_);
    }

    // out = F @ w_out + b_out : <128,128>, 400 blocks, f32 + bias, cmap
    k_gemm<128, 128><<<(B_ * T_ / 128) * (O_ / 128), 256, 0, stream>>>(
        nullptr, Fb, WoutT, out, b_out,
        0, H_, 0, H_, H_, 0, O_, 1, 0, 1, 0, O_ / 128, B_ * T_ / 128);
}